// Round 1
// baseline (803.636 us; speedup 1.0000x reference)
//
#include <hip/hip_runtime.h>

#ifndef __has_builtin
#define __has_builtin(x) 0
#endif
#if __has_builtin(__builtin_amdgcn_fdot2)
#define HAVE_FDOT2 1
#else
#define HAVE_FDOT2 0
#endif

typedef _Float16 f16x2 __attribute__((ext_vector_type(2)));

#define B_   16
#define C_   256
#define H_   48
#define W_   64
#define ND   21          // displacements per axis (441 total)

#define BDIM 384         // 8 dy-slots x 3 dx-groups x 16 w-groups
#define C2T  8           // c-pairs per staged chunk
#define NCHUNK 16        // 128 c-pairs / 8
#define JJN  56          // padded jj extent (valid 0..51)

#define IN1_DW (2*128*32)          // 8192 dwords = 32 KB
#define IN2_DW (128*JJN + 64)      // rows m=0..127 with twist pad -> 7232 dw ~28.9 KB

__device__ __forceinline__ unsigned int packh2(float a, float b) {
    union { f16x2 h; unsigned int u; } u;
    u.h.x = (_Float16)a;
    u.h.y = (_Float16)b;
    return u.u;
}

__device__ __forceinline__ float dot2(unsigned int a, unsigned int b, float c) {
    union { unsigned int u; f16x2 h; } ua, ub;
    ua.u = a; ub.u = b;
#if HAVE_FDOT2
    return __builtin_amdgcn_fdot2(ua.h, ub.h, c, false);
#else
    return c + (float)ua.h.x * (float)ub.h.x + (float)ua.h.y * (float)ub.h.y;
#endif
}

// LDS row index for in2: m = ((slot*2+p)*C2T + c2o); small twist decorrelates
// the p-rows' banks while keeping 16B alignment (twist is a multiple of 4 dw).
__device__ __forceinline__ int in2row(int m) {
    return m * JJN + (((m >> 3) & 1) << 2);
}

__global__ __launch_bounds__(BDIM, 3) void corr_kernel(
    const float* __restrict__ in1, const float* __restrict__ in2,
    float* __restrict__ out)
{
    __shared__ __align__(16) unsigned int s_in1[IN1_DW];
    __shared__ __align__(16) unsigned int s_in2[IN2_DW];

    const int tid = threadIdx.x;
    // bijective XCD swizzle: 768 = 8 * 96; each XCD gets 2 consecutive b values
    int bid = blockIdx.x;
    int sw  = (bid & 7) * 96 + (bid >> 3);
    const int b = sw / H_;
    const int h = sw - b * H_;

    // valid dy range: 0 <= h + 2*dy - 20 < 48
    int dylo = (h < 20) ? ((21 - h) >> 1) : 0;
    int dyhi = min(ND - 1, (67 - h) >> 1) + 1;
    const int V = dyhi - dylo;

    // thread mapping
    const int wg   = tid & 15;
    const int p    = wg & 1;            // w parity
    const int widx = (wg >> 1) << 2;    // parity-index base: 0,4,...,28
    const int t2   = tid >> 4;          // 0..23
    const int dxg  = t2 % 3;
    const int slot = t2 / 3;            // dy slot 0..7
    const int dxb  = dxg << 3;          // dx base 0,8,16

    const float* in1b = in1 + (size_t)b * C_ * H_ * W_;
    const float* in2b = in2 + (size_t)b * C_ * H_ * W_;
    float* outb = out + (size_t)b * (ND * ND) * H_ * W_;

    // ---- zero the all-OOB dy planes (row fully outside image) ----
    {
        int nz = ND - V;
        for (int j = tid; j < nz * ND * W_; j += BDIM) {
            int zi  = j / (ND * W_);
            int rem = j - zi * (ND * W_);
            int dy  = (zi < dylo) ? zi : (dyhi + (zi - dylo));
            int dx  = rem >> 6;
            int w   = rem & 63;
            outb[((size_t)(dy * ND + dx) * H_ + h) * W_ + w] = 0.0f;
        }
    }

    // ---- stage in1 row, parity-packed fp16 pairs (c,c+1) ----
    for (int i = tid; i < 64 * 128; i += BDIM) {
        int w  = i & 63;
        int c2 = i >> 6;
        float f0 = in1b[((size_t)(2 * c2)     * H_ + h) * W_ + w];
        float f1 = in1b[((size_t)(2 * c2 + 1) * H_ + h) * W_ + w];
        int pp = w & 1, wq = w >> 1;
        s_in1[(pp * 128 + c2) * 32 + wq] = packh2(f0, f1);
    }
    // first chunk barrier (below) makes these visible

    const int nR = (V + 7) >> 3;
    for (int round = 0; round < nR; ++round) {
        const int dy0   = dylo + (round << 3);
        const int mydy  = dy0 + slot;
        const bool valid = (mydy < dyhi);

        float acc[4][8];
        #pragma unroll
        for (int i = 0; i < 4; ++i)
            #pragma unroll
            for (int j = 0; j < 8; ++j) acc[i][j] = 0.0f;

        for (int ch = 0; ch < NCHUNK; ++ch) {
            const int c2b = ch * C2T;
            __syncthreads();
            // stage in2 chunk: 8 rows x 2 parities x C2T c-pairs x 56 jj
            for (int i = tid; i < 8 * 2 * C2T * 112 / 2; i += BDIM) {
                int jj2 = i % 112;            // (p, jj) interleave -> w2 consecutive
                int t   = i / 112;
                int pp  = jj2 & 1;
                int jj  = jj2 >> 1;
                int c2o = t % C2T;
                int sl  = t / C2T;
                int dy  = dy0 + sl;
                if (dy >= dyhi) continue;     // slot unused this round
                int w2  = jj2 - 20;           // = pp + 2*jj - 20
                unsigned int val = 0;
                if (w2 >= 0 && w2 < W_) {
                    int r = h + 2 * dy - 20;  // guaranteed in [0,48)
                    int c = 2 * (c2b + c2o);
                    const float* src = &in2b[((size_t)c * H_ + r) * W_ + w2];
                    val = packh2(src[0], src[H_ * W_]);
                }
                s_in2[in2row((sl * 2 + pp) * C2T + c2o) + jj] = val;
            }
            __syncthreads();
            if (valid) {
                const int base1 = (p * 128 + c2b) * 32 + widx;
                #pragma unroll
                for (int c2o = 0; c2o < C2T; ++c2o) {
                    uint4 a4 = *(const uint4*)&s_in1[base1 + c2o * 32];
                    const unsigned int* vr =
                        &s_in2[in2row((slot * 2 + p) * C2T + c2o) + widx + dxb];
                    uint4 v0 = *(const uint4*)(vr);
                    uint4 v1 = *(const uint4*)(vr + 4);
                    uint4 v2 = *(const uint4*)(vr + 8);
                    unsigned int av[4]  = {a4.x, a4.y, a4.z, a4.w};
                    unsigned int vv[12] = {v0.x, v0.y, v0.z, v0.w,
                                           v1.x, v1.y, v1.z, v1.w,
                                           v2.x, v2.y, v2.z, v2.w};
                    #pragma unroll
                    for (int wi = 0; wi < 4; ++wi)
                        #pragma unroll
                        for (int di = 0; di < 8; ++di)
                            acc[wi][di] = dot2(av[wi], vv[wi + di], acc[wi][di]);
                }
            }
        }

        // ---- writeback via LDS bounce (aliases s_in2) for coalesced stores ----
        float* s_out = (float*)s_in2;
        for (int half = 0; half < 2; ++half) {
            __syncthreads();
            if (((slot >> 2) == half) && valid) {
                #pragma unroll
                for (int wi = 0; wi < 4; ++wi)
                    #pragma unroll
                    for (int di = 0; di < 8; ++di) {
                        int dx = dxb + di;
                        if (dx < ND) {
                            int w = p + ((widx + wi) << 1);
                            s_out[(((slot & 3) * ND + dx) << 6) + w] =
                                acc[wi][di] * (1.0f / 256.0f);
                        }
                    }
            }
            __syncthreads();
            int dyb = dy0 + (half << 2);
            for (int j = tid; j < 4 * ND * W_; j += BDIM) {
                int s  = j / (ND * W_);
                int dy = dyb + s;
                if (dy < dyhi) {
                    int rem = j - s * (ND * W_);
                    int dx  = rem >> 6;
                    int w   = rem & 63;
                    outb[((size_t)(dy * ND + dx) * H_ + h) * W_ + w] = s_out[j];
                }
            }
        }
    }
}

extern "C" void kernel_launch(void* const* d_in, const int* in_sizes, int n_in,
                              void* d_out, int out_size, void* d_ws, size_t ws_size,
                              hipStream_t stream) {
    (void)in_sizes; (void)n_in; (void)out_size; (void)d_ws; (void)ws_size;
    const float* in1 = (const float*)d_in[0];
    const float* in2 = (const float*)d_in[1];
    float* out = (float*)d_out;
    dim3 grid(B_ * H_);
    dim3 block(BDIM);
    hipLaunchKernelGGL(corr_kernel, grid, block, 0, stream, in1, in2, out);
}

// Round 3
// 77.845 us; speedup vs baseline: 10.3235x; 10.3235x over previous
//
#include <hip/hip_runtime.h>

#ifndef __has_builtin
#define __has_builtin(x) 0
#endif
#if __has_builtin(__builtin_amdgcn_fdot2)
#define HAVE_FDOT2 1
#else
#define HAVE_FDOT2 0
#endif

#define AS1q __attribute__((address_space(1)))
#define AS3q __attribute__((address_space(3)))

typedef _Float16 f16;
typedef _Float16 f16x2 __attribute__((ext_vector_type(2)));
typedef _Float16 f16x8 __attribute__((ext_vector_type(8)));
typedef float    f32x4 __attribute__((ext_vector_type(4)));
typedef float    f32x2 __attribute__((ext_vector_type(2)));
typedef unsigned int u32x4 __attribute__((ext_vector_type(4)));

#define Bn 16
#define Cn 256
#define Hn 48
#define Wn 64
#define NDISP 21
#define SLAB 32768                      // bytes per (b,row) slab: 4 kc * 2 par * 32 w' * 64 c * 2B
#define WS_NEED ((size_t)2 * Bn * Hn * SLAB)

// ============================================================================
// Conversion kernel: f32 [b][c][row][w]  ->  f16 ws slabs
// slab(b,row) layout: [kc(4)][par(2)][w'(32)][cl(64) f16], byte-in-row XOR-swizzled:
//   beta = (cl*2) ^ ((w'&7)<<4)
// in1 slabs: i = b*48+row in [0,768); in2 slabs: 768 + b*48+row.
// Thread map: cs = t&7 (c-group), wq = t>>3 (w') -> each wave writes 1KB contig.
// ============================================================================
__global__ __launch_bounds__(256) void convert_kernel(const float* __restrict__ in1,
                                                      const float* __restrict__ in2,
                                                      char* __restrict__ ws)
{
    int i = blockIdx.x;                         // 0..1535
    const float* src = (i < Bn * Hn) ? in1 : in2;
    int j = (i < Bn * Hn) ? i : i - Bn * Hn;
    int b = j / Hn, row = j % Hn;
    char* dslab = ws + (size_t)i * SLAB;
    int t  = threadIdx.x;
    int cs = t & 7;                             // 0..7 : 8-c chunk
    int wq = t >> 3;                            // 0..31: w'
    int beta = (cs * 16) ^ ((wq & 7) << 4);
    const float* srcb = src + ((size_t)b * Cn * Hn + row) * Wn;
    #pragma unroll
    for (int kc = 0; kc < 4; ++kc) {
        union { f16 h[8]; u32x4 u; } e0, e1;
        #pragma unroll
        for (int jj = 0; jj < 8; ++jj) {
            int c = kc * 64 + cs * 8 + jj;
            f32x2 v = *(const f32x2*)&srcb[(size_t)c * Hn * Wn + 2 * wq];
            e0.h[jj] = (f16)v.x;                // even w  (par 0)
            e1.h[jj] = (f16)v.y;                // odd  w  (par 1)
        }
        char* d = dslab + kc * 8192;
        *(u32x4*)(d +        wq * 128 + beta) = e0.u;
        *(u32x4*)(d + 4096 + wq * 128 + beta) = e1.u;
    }
}

// ============================================================================
// Main MFMA kernel. Block = (b,h), 8 waves; wave wv owns dy in {wv, wv+8, wv+16}.
// Per valid dy: two 32x32 parity Grams G_p = A_p^T B_p (K=256) via
// mfma_f32_16x16x32_f16; A-frags in registers; B staged by per-wave
// global_load_lds double-buffer (8 KB chunks, load-only counted vmcnt).
// out[dx][w=2m+p] = G_p[m][m+dx-10] / 256.
// ============================================================================
__device__ __forceinline__ void dma8(const char* gsrc, char* ldst)
{
    #pragma unroll
    for (int i2 = 0; i2 < 8; ++i2)
        __builtin_amdgcn_global_load_lds((const AS1q void*)(gsrc + i2 * 1024),
                                         (AS3q void*)(ldst + i2 * 1024), 16, 0, 0);
}

__global__ __launch_bounds__(512, 1) void corr_mfma(const char* __restrict__ ws,
                                                    float* __restrict__ out)
{
    __shared__ char lds[8][16384];              // per-wave: 2 x 8KB chunk buffers
    const int tid = threadIdx.x;
    const int wv  = tid >> 6;
    const int l   = tid & 63;
    const int nl  = l & 15;
    const int g   = l >> 4;

    int bid = blockIdx.x;                       // bijective XCD swizzle (768 = 8*96)
    int sw  = (bid & 7) * 96 + (bid >> 3);
    int b = sw / Hn, h = sw % Hn;

    const char* ws1 = ws;
    const char* ws2 = ws + (size_t)Bn * Hn * SLAB;
    float* outb = out + (size_t)b * (NDISP * NDISP) * Hn * Wn;

    // ---- zero planes for this wave's invalid dy ----
    {
        f32x4 z = {0.f, 0.f, 0.f, 0.f};
        for (int dy = wv; dy < NDISP; dy += 8) {
            int r = h + 2 * dy - 20;
            if (r < 0 || r >= Hn) {
                #pragma unroll
                for (int i2 = 0; i2 < 6; ++i2) {
                    int dxr = i2 * 4 + g;
                    if (dxr < NDISP)
                        *(f32x4*)&outb[((size_t)(dy * NDISP + dxr) * Hn + h) * Wn + nl * 4] = z;
                }
            }
        }
    }

    // ---- A-fragments into registers (held for the whole kernel) ----
    const char* aslab = ws1 + (size_t)(b * Hn + h) * SLAB;
    f16x8 af[2][2][8];                          // [par][mi][kiter]
    #pragma unroll
    for (int p = 0; p < 2; ++p)
        #pragma unroll
        for (int mi = 0; mi < 2; ++mi) {
            int w = mi * 16 + nl;
            #pragma unroll
            for (int k = 0; k < 8; ++k) {
                int cl2 = ((k & 1) * 32 + g * 8) * 2;
                af[p][mi][k] = *(const f16x8*)(aslab + (k >> 1) * 8192 + p * 4096
                                               + w * 128 + (cl2 ^ ((w & 7) << 4)));
            }
        }

    // ---- valid-dy range for this wave: dy = wv + 8k, k in [klo, khi] ----
    int t0  = 20 - h - 2 * wv;
    int klo = (t0 > 0) ? ((t0 + 15) >> 4) : 0;
    int khi = (67 - h - 2 * wv) >> 4;
    int kdy = (20 - wv) >> 3;
    if (kdy < khi) khi = kdy;
    int ng = khi - klo + 1;

    asm volatile("s_waitcnt vmcnt(0)" ::: "memory");   // drain zero-stores + A-loads
    if (ng <= 0) return;

    char* wlds = &lds[wv][0];

    // B-frag LDS offsets (within a chunk buffer)
    int boff[2][2][2];                          // [par][ni][kk]
    #pragma unroll
    for (int p2 = 0; p2 < 2; ++p2)
        #pragma unroll
        for (int ni = 0; ni < 2; ++ni)
            #pragma unroll
            for (int kk = 0; kk < 2; ++kk) {
                int w2  = ni * 16 + nl;
                int cl2 = (kk * 32 + g * 8) * 2;
                boff[p2][ni][kk] = p2 * 4096 + w2 * 128 + (cl2 ^ ((w2 & 7) << 4));
            }

    // prologue: first chunk of first gram -> buf0
    {
        int dy0 = wv + 8 * klo;
        int r0  = h + 2 * dy0 - 20;
        dma8(ws2 + (size_t)(b * Hn + r0) * SLAB + l * 16, wlds);
    }

    for (int gi = 0; gi < ng; ++gi) {
        int dy = wv + 8 * (klo + gi);
        int r  = h + 2 * dy - 20;
        const char* gs = ws2 + (size_t)(b * Hn + r) * SLAB + l * 16;

        f32x4 acc[2][2][2];                     // [par][mi][ni]
        #pragma unroll
        for (int p2 = 0; p2 < 2; ++p2)
            #pragma unroll
            for (int mi = 0; mi < 2; ++mi)
                #pragma unroll
                for (int ni = 0; ni < 2; ++ni)
                    acc[p2][mi][ni] = (f32x4){0.f, 0.f, 0.f, 0.f};

        #pragma unroll
        for (int c = 0; c < 4; ++c) {
            // issue next chunk's DMA (chunk c uses buf c&1; next goes to (c+1)&1)
            bool tail = false;
            if (c < 3) {
                dma8(gs + (c + 1) * 8192, wlds + ((c + 1) & 1) * 8192);
            } else if (gi + 1 < ng) {
                int rn = h + 2 * (wv + 8 * (klo + gi + 1)) - 20;
                dma8(ws2 + (size_t)(b * Hn + rn) * SLAB + l * 16, wlds); // -> buf0
            } else {
                tail = true;
            }
            // Load-only accounting: at each wait, the loads still possibly in
            // flight are [this chunk's 8][next 8 just issued] -> vmcnt(8)
            // guarantees this chunk arrived (loads retire in order; any store
            // retirement only lowers the count -> still safe).
            if (tail) asm volatile("s_waitcnt vmcnt(0)" ::: "memory");
            else      asm volatile("s_waitcnt vmcnt(8)" ::: "memory");

            char* bb = wlds + (c & 1) * 8192;
            #pragma unroll
            for (int kk = 0; kk < 2; ++kk) {
                f16x8 bf[2][2];
                #pragma unroll
                for (int p2 = 0; p2 < 2; ++p2)
                    #pragma unroll
                    for (int ni = 0; ni < 2; ++ni)
                        bf[p2][ni] = *(const f16x8*)(bb + boff[p2][ni][kk]);
                #pragma unroll
                for (int p2 = 0; p2 < 2; ++p2)
                    #pragma unroll
                    for (int mi = 0; mi < 2; ++mi)
                        #pragma unroll
                        for (int ni = 0; ni < 2; ++ni)
                            acc[p2][mi][ni] = __builtin_amdgcn_mfma_f32_16x16x32_f16(
                                af[p2][mi][c * 2 + kk], bf[p2][ni], acc[p2][mi][ni], 0, 0, 0);
            }
        }

        // ---- extraction via LDS bounce (reuses buf1, which is now dead).
        // Compiler memory barriers between phases: the zero-fill / scalar
        // scatter / vector reads use different types, so without these TBAA
        // lets clang reorder them (R2's correctness bug).
        float* bounce = (float*)(wlds + 8192);
        #pragma unroll
        for (int i2 = 0; i2 < 6; ++i2)
            *(f32x4*)((char*)bounce + i2 * 1024 + l * 16) = (f32x4){0.f, 0.f, 0.f, 0.f};
        asm volatile("" ::: "memory");
        #pragma unroll
        for (int p2 = 0; p2 < 2; ++p2)
            #pragma unroll
            for (int mi = 0; mi < 2; ++mi)
                #pragma unroll
                for (int ni = 0; ni < 2; ++ni)
                    #pragma unroll
                    for (int rr = 0; rr < 4; ++rr) {
                        int o = nl + ((ni - mi) << 4) - 4 * g - rr;   // dx - 10
                        if (o >= -10 && o <= 10) {
                            int m = mi * 16 + 4 * g + rr;
                            bounce[(o + 10) * 64 + 2 * m + p2] = acc[p2][mi][ni][rr];
                        }
                    }
        asm volatile("" ::: "memory");
        #pragma unroll
        for (int i2 = 0; i2 < 6; ++i2) {        // 6 global stores, drained next gram
            int dxr = i2 * 4 + g;
            f32x4 v = *(f32x4*)&bounce[dxr * 64 + nl * 4];
            v = v * (1.0f / 256.0f);
            if (dxr < NDISP)
                *(f32x4*)&outb[((size_t)(dy * NDISP + dxr) * Hn + h) * Wn + nl * 4] = v;
        }
    }
}

// ============================================================================
// Fallback (round-1 kernel, known-good) if ws_size is too small.
// ============================================================================
#define BDIM 384
#define C2T  8
#define NCHUNK 16
#define JJN  56
#define IN1_DW (2*128*32)
#define IN2_DW (128*JJN + 64)

__device__ __forceinline__ unsigned int packh2(float a, float b) {
    union { f16x2 h; unsigned int u; } u;
    u.h.x = (_Float16)a; u.h.y = (_Float16)b;
    return u.u;
}
__device__ __forceinline__ float dot2(unsigned int a, unsigned int b, float c) {
    union { unsigned int u; f16x2 h; } ua, ub;
    ua.u = a; ub.u = b;
#if HAVE_FDOT2
    return __builtin_amdgcn_fdot2(ua.h, ub.h, c, false);
#else
    return c + (float)ua.h.x * (float)ub.h.x + (float)ua.h.y * (float)ub.h.y;
#endif
}
__device__ __forceinline__ int in2row(int m) { return m * JJN + (((m >> 3) & 1) << 2); }

__global__ __launch_bounds__(BDIM, 3) void corr_fallback(
    const float* __restrict__ in1, const float* __restrict__ in2,
    float* __restrict__ out)
{
    __shared__ __align__(16) unsigned int s_in1[IN1_DW];
    __shared__ __align__(16) unsigned int s_in2[IN2_DW];
    const int tid = threadIdx.x;
    int bid = blockIdx.x;
    int sw  = (bid & 7) * 96 + (bid >> 3);
    const int b = sw / Hn;
    const int h = sw - b * Hn;
    int dylo = (h < 20) ? ((21 - h) >> 1) : 0;
    int dyhi = min(NDISP - 1, (67 - h) >> 1) + 1;
    const int V = dyhi - dylo;
    const int wg   = tid & 15;
    const int p    = wg & 1;
    const int widx = (wg >> 1) << 2;
    const int t2   = tid >> 4;
    const int dxg  = t2 % 3;
    const int slot = t2 / 3;
    const int dxb  = dxg << 3;
    const float* in1b = in1 + (size_t)b * Cn * Hn * Wn;
    const float* in2b = in2 + (size_t)b * Cn * Hn * Wn;
    float* outb = out + (size_t)b * (NDISP * NDISP) * Hn * Wn;
    {
        int nz = NDISP - V;
        for (int j = tid; j < nz * NDISP * Wn; j += BDIM) {
            int zi  = j / (NDISP * Wn);
            int rem = j - zi * (NDISP * Wn);
            int dy  = (zi < dylo) ? zi : (dyhi + (zi - dylo));
            int dx  = rem >> 6;
            int w   = rem & 63;
            outb[((size_t)(dy * NDISP + dx) * Hn + h) * Wn + w] = 0.0f;
        }
    }
    for (int i = tid; i < 64 * 128; i += BDIM) {
        int w  = i & 63;
        int c2 = i >> 6;
        float f0 = in1b[((size_t)(2 * c2)     * Hn + h) * Wn + w];
        float f1 = in1b[((size_t)(2 * c2 + 1) * Hn + h) * Wn + w];
        int pp = w & 1, wq = w >> 1;
        s_in1[(pp * 128 + c2) * 32 + wq] = packh2(f0, f1);
    }
    const int nR = (V + 7) >> 3;
    for (int round = 0; round < nR; ++round) {
        const int dy0   = dylo + (round << 3);
        const int mydy  = dy0 + slot;
        const bool valid = (mydy < dyhi);
        float acc[4][8];
        #pragma unroll
        for (int i = 0; i < 4; ++i)
            #pragma unroll
            for (int j = 0; j < 8; ++j) acc[i][j] = 0.0f;
        for (int ch = 0; ch < NCHUNK; ++ch) {
            const int c2b = ch * C2T;
            __syncthreads();
            for (int i = tid; i < 8 * 2 * C2T * 112 / 2; i += BDIM) {
                int jj2 = i % 112;
                int t   = i / 112;
                int pp  = jj2 & 1;
                int jj  = jj2 >> 1;
                int c2o = t % C2T;
                int sl  = t / C2T;
                int dy  = dy0 + sl;
                if (dy >= dyhi) continue;
                int w2  = jj2 - 20;
                unsigned int val = 0;
                if (w2 >= 0 && w2 < Wn) {
                    int rr = h + 2 * dy - 20;
                    int c = 2 * (c2b + c2o);
                    const float* srcp = &in2b[((size_t)c * Hn + rr) * Wn + w2];
                    val = packh2(srcp[0], srcp[Hn * Wn]);
                }
                s_in2[in2row((sl * 2 + pp) * C2T + c2o) + jj] = val;
            }
            __syncthreads();
            if (valid) {
                const int base1 = (p * 128 + c2b) * 32 + widx;
                #pragma unroll
                for (int c2o = 0; c2o < C2T; ++c2o) {
                    u32x4 a4 = *(const u32x4*)&s_in1[base1 + c2o * 32];
                    const unsigned int* vr =
                        &s_in2[in2row((slot * 2 + p) * C2T + c2o) + widx + dxb];
                    u32x4 v0 = *(const u32x4*)(vr);
                    u32x4 v1 = *(const u32x4*)(vr + 4);
                    u32x4 v2 = *(const u32x4*)(vr + 8);
                    unsigned int av[4]  = {a4.x, a4.y, a4.z, a4.w};
                    unsigned int vv[12] = {v0.x, v0.y, v0.z, v0.w,
                                           v1.x, v1.y, v1.z, v1.w,
                                           v2.x, v2.y, v2.z, v2.w};
                    #pragma unroll
                    for (int wi = 0; wi < 4; ++wi)
                        #pragma unroll
                        for (int di = 0; di < 8; ++di)
                            acc[wi][di] = dot2(av[wi], vv[wi + di], acc[wi][di]);
                }
            }
        }
        float* s_out = (float*)s_in2;
        for (int half = 0; half < 2; ++half) {
            __syncthreads();
            if (((slot >> 2) == half) && valid) {
                #pragma unroll
                for (int wi = 0; wi < 4; ++wi)
                    #pragma unroll
                    for (int di = 0; di < 8; ++di) {
                        int dx = dxb + di;
                        if (dx < NDISP) {
                            int w = p + ((widx + wi) << 1);
                            s_out[(((slot & 3) * NDISP + dx) << 6) + w] =
                                acc[wi][di] * (1.0f / 256.0f);
                        }
                    }
            }
            __syncthreads();
            int dyb = dy0 + (half << 2);
            for (int j = tid; j < 4 * NDISP * Wn; j += BDIM) {
                int s  = j / (NDISP * Wn);
                int dy = dyb + s;
                if (dy < dyhi) {
                    int rem = j - s * (NDISP * Wn);
                    int dx  = rem >> 6;
                    int w   = rem & 63;
                    outb[((size_t)(dy * NDISP + dx) * Hn + h) * Wn + w] = s_out[j];
                }
            }
        }
    }
}

extern "C" void kernel_launch(void* const* d_in, const int* in_sizes, int n_in,
                              void* d_out, int out_size, void* d_ws, size_t ws_size,
                              hipStream_t stream) {
    (void)in_sizes; (void)n_in; (void)out_size;
    const float* in1 = (const float*)d_in[0];
    const float* in2 = (const float*)d_in[1];
    float* out = (float*)d_out;
    if (ws_size >= WS_NEED) {
        convert_kernel<<<dim3(2 * Bn * Hn), dim3(256), 0, stream>>>(in1, in2, (char*)d_ws);
        corr_mfma<<<dim3(Bn * Hn), dim3(512), 0, stream>>>((const char*)d_ws, out);
    } else {
        corr_fallback<<<dim3(Bn * Hn), dim3(BDIM), 0, stream>>>(in1, in2, out);
    }
}